// Round 10
// baseline (239.787 us; speedup 1.0000x reference)
//
#include <hip/hip_runtime.h>

// MHA forward: x[2,4096,768] -> out[2,4096,768], 8 heads, head_dim 96.
// R10 = R9's LDS-efficiency (64 q/wave, pre-swizzled HBM K/V, global_load_lds
// staging, XCD-chunked L2 residency) + restored TLP: 2-wave blocks, grid 512,
// 2 blocks/CU -> 2 waves/SIMD so softmax/LDS of one wave overlaps MFMA of the
// other (R9 at 1 wave/SIMD serialized the whole chain: MfmaUtil 27%, slower).

typedef __bf16 bf16;
typedef __attribute__((ext_vector_type(4))) float f32x4;
typedef __attribute__((ext_vector_type(16))) float f32x16;
typedef __attribute__((ext_vector_type(8))) __bf16 bf16x8;
typedef __attribute__((ext_vector_type(4))) __bf16 bf16x4;
typedef __attribute__((ext_vector_type(4))) unsigned u32x4;

#define EMB 768
#define SEQ 4096
#define NB 2
#define NHEADS 8
#define HD 96
#define BHTOT (NB * NHEADS)     // 16
#define MTOT (NB * SEQ)         // 8192
// softmax scale folded into Q gemm epilogue, in exp2 domain:
#define QSCALE 0.14724241052735512f   // 96^-0.5 * log2(e)

#define AS1 __attribute__((address_space(1)))
#define AS3 __attribute__((address_space(3)))

// ---------------- fp32 -> bf16 cast (x) ----------------
__global__ __launch_bounds__(256) void cast_f32_bf16(const float* __restrict__ in,
                                                     bf16* __restrict__ out) {
  const int i = (blockIdx.x * 256 + threadIdx.x) * 4;
  const f32x4 v = *reinterpret_cast<const f32x4*>(in + i);
  bf16x4 o;
  o[0] = (bf16)v[0]; o[1] = (bf16)v[1]; o[2] = (bf16)v[2]; o[3] = (bf16)v[3];
  *reinterpret_cast<bf16x4*>(out + i) = o;
}

// ---------------- fused 4-weight cast ----------------
__global__ __launch_bounds__(256) void cast_w4(const float* __restrict__ w0,
                                               const float* __restrict__ w1,
                                               const float* __restrict__ w2,
                                               const float* __restrict__ w3,
                                               bf16* __restrict__ o0,
                                               bf16* __restrict__ o1,
                                               bf16* __restrict__ o2,
                                               bf16* __restrict__ o3) {
  const float* w = (blockIdx.y == 0) ? w0 : (blockIdx.y == 1) ? w1 : (blockIdx.y == 2) ? w2 : w3;
  bf16* o = (blockIdx.y == 0) ? o0 : (blockIdx.y == 1) ? o1 : (blockIdx.y == 2) ? o2 : o3;
  const int i = (blockIdx.x * 256 + threadIdx.x) * 4;
  const f32x4 v = *reinterpret_cast<const f32x4*>(w + i);
  bf16x4 ob;
  ob[0] = (bf16)v[0]; ob[1] = (bf16)v[1]; ob[2] = (bf16)v[2]; ob[3] = (bf16)v[3];
  *reinterpret_cast<bf16x4*>(o + i) = ob;
}

// ---------------- GEMM ----------------
// MODE 0: fused QKV. B is [2304][768] (Wq;Wk;Wv contiguous).
//   Q (scaled) -> out[bh][n][96]; V -> out + MTOT*EMB, same layout;
//   K -> outK[bh][n][128]: padded row, 16B-slot XOR-swizzled by (n&7).
// MODE 1: C[M,768] = A*Wo^T + b0, fp32 row-major to out.
template <int MODE>
__global__ __launch_bounds__(256) void gemm_bt(const bf16* __restrict__ A,
                                               const bf16* __restrict__ B,
                                               const float* __restrict__ b0,
                                               const float* __restrict__ b1,
                                               const float* __restrict__ b2,
                                               void* __restrict__ out,
                                               void* __restrict__ outK) {
  constexpr int K = EMB;
  __shared__ bf16 As[128 * 32];
  __shared__ bf16 Bs[128 * 32];
  const int tid = threadIdx.x;
  const int lane = tid & 63;
  const int wid = tid >> 6;
  const int wr = wid >> 1, wc = wid & 1;
  const int l15 = lane & 15, l4 = lane >> 4;
  const int rowBase = blockIdx.y * 128;
  const int colBase = blockIdx.x * 128;

  f32x4 acc[4][4] = {};

  for (int kt = 0; kt < K / 32; ++kt) {
    const int kb = kt * 32;
#pragma unroll
    for (int i = 0; i < 2; ++i) {
      const int c = (wid * 2 + i) * 64 + lane;
      const int row = c >> 2, cc = c & 3;
      const bf16* ga = A + (size_t)(rowBase + row) * K + kb + cc * 8;
      const bf16* gb = B + (size_t)(colBase + row) * K + kb + cc * 8;
      __builtin_amdgcn_global_load_lds(
          (const AS1 void*)ga,
          (AS3 void*)(As + (size_t)(wid * 2 + i) * 512), 16, 0, 0);
      __builtin_amdgcn_global_load_lds(
          (const AS1 void*)gb,
          (AS3 void*)(Bs + (size_t)(wid * 2 + i) * 512), 16, 0, 0);
    }
    __syncthreads();
    bf16x8 af[4], bfr[4];
#pragma unroll
    for (int t = 0; t < 4; ++t) {
      af[t]  = *reinterpret_cast<const bf16x8*>(As + (wr * 64 + t * 16 + l15) * 32 + l4 * 8);
      bfr[t] = *reinterpret_cast<const bf16x8*>(Bs + (wc * 64 + t * 16 + l15) * 32 + l4 * 8);
    }
#pragma unroll
    for (int mt = 0; mt < 4; ++mt)
#pragma unroll
      for (int nt = 0; nt < 4; ++nt)
        acc[mt][nt] = __builtin_amdgcn_mfma_f32_16x16x32_bf16(af[mt], bfr[nt], acc[mt][nt], 0, 0, 0);
    __syncthreads();
  }

#pragma unroll
  for (int mt = 0; mt < 4; ++mt) {
#pragma unroll
    for (int nt = 0; nt < 4; ++nt) {
      const int gn = colBase + wc * 64 + nt * 16 + l15;
      if (MODE == 0) {
        const int mm = gn / 768;
        const int g7 = gn - mm * 768;
        const int h = g7 / HD, d = g7 - h * HD;
        const float* bp = (mm == 0) ? b0 : (mm == 1) ? b1 : b2;
        const float bv = bp[g7];
        const float sc = (mm == 0) ? QSCALE : 1.f;
#pragma unroll
        for (int r = 0; r < 4; ++r) {
          const int gm = rowBase + wr * 64 + mt * 16 + l4 * 4 + r;
          const int b = gm >> 12, n = gm & (SEQ - 1);
          const float v = (acc[mt][nt][r] + bv) * sc;
          if (mm == 1) {  // K: padded + swizzled [bh][n][128]
            ((bf16*)outK)[((size_t)(b * NHEADS + h) * SEQ + n) * 128 +
                          (((d >> 3) ^ (n & 7)) << 3) + (d & 7)] = (bf16)v;
          } else {        // Q at 0, V at +MTOT*EMB
            bf16* dst = (bf16*)out + (mm == 2 ? (size_t)MTOT * EMB : 0);
            dst[((size_t)(b * NHEADS + h) * SEQ + n) * HD + d] = (bf16)v;
          }
        }
      } else {
        const float bv = b0[gn];
#pragma unroll
        for (int r = 0; r < 4; ++r) {
          const int gm = rowBase + wr * 64 + mt * 16 + l4 * 4 + r;
          ((float*)out)[(size_t)gm * EMB + gn] = acc[mt][nt][r] + bv;
        }
      }
    }
  }
}

// ---------------- V transpose + ki permute + XOR swizzle ----------------
__global__ __launch_bounds__(256) void transpose_v(const bf16* __restrict__ v,
                                                   bf16* __restrict__ vt) {
  __shared__ bf16 T[96][72];
  const int bh = blockIdx.y;
  const int n0 = blockIdx.x * 64;
  const int tid = threadIdx.x;
#pragma unroll
  for (int i = 0; i < 3; ++i) {
    const int c = i * 256 + tid;
    const int n = c / 12, cc = c % 12;
    const bf16x8 val = *reinterpret_cast<const bf16x8*>(
        v + ((size_t)bh * SEQ + n0 + n) * HD + cc * 8);
#pragma unroll
    for (int j = 0; j < 8; ++j) T[cc * 8 + j][n] = val[j];
  }
  __syncthreads();
#pragma unroll
  for (int i = 0; i < 3; ++i) {
    const int c = i * 256 + tid;
    const int d = c >> 3, nc = c & 7;
    const int s0i = (nc >> 1) * 16 + (nc & 1) * 4;   // ki-permute source
    const bf16x4 lo = *reinterpret_cast<const bf16x4*>(&T[d][s0i]);
    const bf16x4 hi = *reinterpret_cast<const bf16x4*>(&T[d][s0i + 8]);
    const bf16x8 val = __builtin_shufflevector(lo, hi, 0, 1, 2, 3, 4, 5, 6, 7);
    const int pc = nc ^ (d & 7);                     // XOR swizzle
    *reinterpret_cast<bf16x8*>(vt + ((size_t)bh * HD + d) * SEQ + n0 + pc * 8) = val;
  }
}

// ---------------- Flash attention (32x32 MFMA, 64 q/wave, 2-wave blocks) --
// Block = (bh, 128 q), 2 waves x 64 q (2 groups of 32). Grid 512 = 2/CU ->
// 2 waves/SIMD (TLP). KV tile 64, double-buffered, global_load_lds staging
// from pre-swizzled HBM. Lane-local softmax (exp2, no max tracking).
__global__ __launch_bounds__(128) void attn_fwd(const bf16* __restrict__ q,
                                                const bf16* __restrict__ ksw,
                                                const bf16* __restrict__ vt,
                                                bf16* __restrict__ o) {
  __shared__ bf16 Ks[2][64 * 128];   // 2 x 16KB, rows 256B, slot ^= row&7
  __shared__ bf16 Vts[2][96 * 64];   // 2 x 12KB, rows 128B, slot ^= row&7
  const int tid = threadIdx.x;    // 0..127
  const int lane = tid & 63;
  const int wid = tid >> 6;       // 0..1
  const int l31 = lane & 31, lhi = lane >> 5;
  // XCD-chunked bijective remap: 64 consecutive slots per XCD = 2 full bh
  const int lin = blockIdx.y * 32 + blockIdx.x;       // 512 blocks
  const int l2 = (lin & 7) * 64 + (lin >> 3);
  const int qblk = l2 & 31, bh = l2 >> 5;
  const int q0 = qblk * 128 + wid * 64;
  const size_t headq = (size_t)bh * SEQ * HD;
  const bf16* kg = ksw + (size_t)bh * SEQ * 128;
  const bf16* vg = vt + (size_t)bh * (size_t)HD * SEQ;

  // staging source pointers: K linear image (chunk c -> byte c*16);
  // V row d = i*16 + (tid>>3), sub-chunk tid&7.
  const bf16* kp = kg + (size_t)tid * 8;
  const bf16* vp = vg + (size_t)(tid >> 3) * SEQ + (tid & 7) * 8;

  // LDS read byte-offsets (loop-invariant)
  int krd[12], vrd[12];
#pragma unroll
  for (int kib = 0; kib < 2; ++kib)
#pragma unroll
    for (int dc = 0; dc < 6; ++dc) {
      const int row = kib * 32 + l31;
      krd[kib * 6 + dc] = (row * 128 + (((dc * 2 + lhi) ^ (l31 & 7)) * 8)) * 2;
    }
#pragma unroll
  for (int db = 0; db < 3; ++db)
#pragma unroll
    for (int kb = 0; kb < 4; ++kb) {
      const int row = db * 32 + l31;
      vrd[db * 4 + kb] = (row * 64 + (((kb * 2 + lhi) ^ (l31 & 7)) * 8)) * 2;
    }

  // Q B-frags for both q-groups (scale pre-folded into q)
  bf16x8 qf[2][6];
#pragma unroll
  for (int g = 0; g < 2; ++g)
#pragma unroll
    for (int dc = 0; dc < 6; ++dc)
      qf[g][dc] = *reinterpret_cast<const bf16x8*>(
          q + headq + (size_t)(q0 + g * 32 + l31) * HD + dc * 16 + lhi * 8);

  f32x16 oacc[2][3] = {};     // [group][d-block]
  float lrun[2] = {0.f, 0.f};

  // stage tile 0 into buffer 0: K 8 x 2KB rounds, V 6 x 2KB rounds
#pragma unroll
  for (int i = 0; i < 8; ++i)
    __builtin_amdgcn_global_load_lds((const AS1 void*)(kp + i * 1024),
                                     (AS3 void*)(&Ks[0][i * 1024 + tid * 8]), 16, 0, 0);
#pragma unroll
  for (int i = 0; i < 6; ++i)
    __builtin_amdgcn_global_load_lds((const AS1 void*)(vp + (size_t)i * 16 * SEQ),
                                     (AS3 void*)(&Vts[0][i * 1024 + tid * 8]), 16, 0, 0);
  kp += 8192;   // next K tile (64 rows x 128)
  vp += 64;     // next V tile (64 columns)
  __syncthreads();

  constexpr int NT = SEQ / 64;
  for (int kt = 0; kt < NT; ++kt) {
    const int cur = kt & 1;
    // issue next-tile staging into the other buffer (drained by the barrier)
    if (kt < NT - 1) {
#pragma unroll
      for (int i = 0; i < 8; ++i)
        __builtin_amdgcn_global_load_lds((const AS1 void*)(kp + i * 1024),
                                         (AS3 void*)(&Ks[cur ^ 1][i * 1024 + tid * 8]), 16, 0, 0);
#pragma unroll
      for (int i = 0; i < 6; ++i)
        __builtin_amdgcn_global_load_lds((const AS1 void*)(vp + (size_t)i * 16 * SEQ),
                                         (AS3 void*)(&Vts[cur ^ 1][i * 1024 + tid * 8]), 16, 0, 0);
      kp += 8192;
      vp += 64;
    }
    const char* ksb = (const char*)Ks[cur];
    const char* vsb = (const char*)Vts[cur];

    // ---- S^T = K Q^T, softmax, P-pack: per 32-ki block (bounds s regs) ----
    bf16x8 pf[2][4];
#pragma unroll
    for (int kib = 0; kib < 2; ++kib) {
      f32x16 s[2] = {};
      __builtin_amdgcn_s_setprio(1);
#pragma unroll
      for (int dc = 0; dc < 6; ++dc) {
        const bf16x8 kf = *reinterpret_cast<const bf16x8*>(ksb + krd[kib * 6 + dc]);
        s[0] = __builtin_amdgcn_mfma_f32_32x32x16_bf16(kf, qf[0][dc], s[0], 0, 0, 0);
        s[1] = __builtin_amdgcn_mfma_f32_32x32x16_bf16(kf, qf[1][dc], s[1], 0, 0, 0);
      }
      __builtin_amdgcn_s_setprio(0);
#pragma unroll
      for (int g = 0; g < 2; ++g) {
        float a0 = 0.f, a1 = 0.f, a2 = 0.f, a3 = 0.f;
#pragma unroll
        for (int i = 0; i < 4; ++i) {
          s[g][4 * i + 0] = __builtin_amdgcn_exp2f(s[g][4 * i + 0]); a0 += s[g][4 * i + 0];
          s[g][4 * i + 1] = __builtin_amdgcn_exp2f(s[g][4 * i + 1]); a1 += s[g][4 * i + 1];
          s[g][4 * i + 2] = __builtin_amdgcn_exp2f(s[g][4 * i + 2]); a2 += s[g][4 * i + 2];
          s[g][4 * i + 3] = __builtin_amdgcn_exp2f(s[g][4 * i + 3]); a3 += s[g][4 * i + 3];
        }
        lrun[g] += (a0 + a1) + (a2 + a3);
        unsigned c[8];
#pragma unroll
        for (int i = 0; i < 8; ++i)
          asm("v_cvt_pk_bf16_f32 %0, %1, %2"
              : "=v"(c[i]) : "v"(s[g][2 * i]), "v"(s[g][2 * i + 1]));
        const u32x4 wa = {c[0], c[1], c[2], c[3]};
        const u32x4 wb = {c[4], c[5], c[6], c[7]};
        pf[g][kib * 2 + 0] = __builtin_bit_cast(bf16x8, wa);
        pf[g][kib * 2 + 1] = __builtin_bit_cast(bf16x8, wb);
      }
    }

    // ---- O^T += V^T P^T: each V-frag feeds both groups ----
    __builtin_amdgcn_s_setprio(1);
#pragma unroll
    for (int kb = 0; kb < 4; ++kb) {
#pragma unroll
      for (int db = 0; db < 3; ++db) {
        const bf16x8 vf = *reinterpret_cast<const bf16x8*>(vsb + vrd[db * 4 + kb]);
        oacc[0][db] = __builtin_amdgcn_mfma_f32_32x32x16_bf16(vf, pf[0][kb], oacc[0][db], 0, 0, 0);
        oacc[1][db] = __builtin_amdgcn_mfma_f32_32x32x16_bf16(vf, pf[1][kb], oacc[1][db], 0, 0, 0);
      }
    }
    __builtin_amdgcn_s_setprio(0);

    __syncthreads();  // drains staging DMA (vmcnt) + both waves done with cur
  }

  // ---- normalize + write O^T -> o[m][768] ----
  const int b = bh >> 3, h = bh & 7;
#pragma unroll
  for (int g = 0; g < 2; ++g) {
    float lr = lrun[g];
    lr += __shfl_xor(lr, 32, 64);   // combine ki halves
    const float inv = 1.f / lr;
    const int n = q0 + g * 32 + l31;
    bf16* obase = o + (size_t)(b * SEQ + n) * EMB + h * HD;
#pragma unroll
    for (int db = 0; db < 3; ++db) {
#pragma unroll
      for (int i = 0; i < 8; ++i) {
        const int r = 2 * i;
        const int d = db * 32 + (r & 3) + 8 * (r >> 2) + 4 * lhi;
        unsigned w;
        const float v0 = oacc[g][db][r] * inv, v1 = oacc[g][db][r + 1] * inv;
        asm("v_cvt_pk_bf16_f32 %0, %1, %2" : "=v"(w) : "v"(v0), "v"(v1));
        *reinterpret_cast<unsigned*>(obase + d) = w;
      }
    }
  }
}

// ---------------- launch ----------------
extern "C" void kernel_launch(void* const* d_in, const int* in_sizes, int n_in,
                              void* d_out, int out_size, void* d_ws, size_t ws_size,
                              hipStream_t stream) {
  const float* x  = (const float*)d_in[0];
  const float* Wq = (const float*)d_in[1];
  const float* bq = (const float*)d_in[2];
  const float* Wk = (const float*)d_in[3];
  const float* bk = (const float*)d_in[4];
  const float* Wv = (const float*)d_in[5];
  const float* bv = (const float*)d_in[6];
  const float* Wo = (const float*)d_in[7];
  const float* bo = (const float*)d_in[8];

  const size_t XN = (size_t)MTOT * EMB;        // 6291456
  const size_t WN = (size_t)EMB * EMB;         // 589824
  const size_t KSWN = (size_t)BHTOT * SEQ * 128;  // 8388608 (padded K)

  bf16* p = (bf16*)d_ws;
  bf16* xbf  = p; p += XN;
  bf16* wqb  = p; p += WN;   // wq/wk/wv contiguous -> fused B [2304][768]
  bf16* wkb  = p; p += WN;
  bf16* wvb  = p; p += WN;
  bf16* wob  = p; p += WN;
  bf16* qb   = p; p += XN;   // Q [bh][n][96]
  bf16* vb   = p; p += XN;   // V [bh][n][96]  (qb and vb contiguous)
  bf16* kbsw = p; p += KSWN; // K padded+swizzled [bh][n][128]
  bf16* vtb  = p; p += XN;   // Vt permuted+swizzled [bh][96][n]
  bf16* ao   = p; p += XN;   // attention output [m][768]

  cast_f32_bf16<<<XN / 1024, 256, 0, stream>>>(x, xbf);
  cast_w4<<<dim3(WN / 1024, 4), 256, 0, stream>>>(Wq, Wk, Wv, Wo, wqb, wkb, wvb, wob);

  gemm_bt<0><<<dim3(3 * EMB / 128, MTOT / 128), 256, 0, stream>>>(
      xbf, wqb, bq, bk, bv, qb, kbsw);

  transpose_v<<<dim3(SEQ / 64, BHTOT), 256, 0, stream>>>(vb, vtb);

  attn_fwd<<<dim3(32, BHTOT), 128, 0, stream>>>(qb, kbsw, vtb, ao);

  gemm_bt<1><<<dim3(EMB / 128, MTOT / 128), 256, 0, stream>>>(
      ao, wob, bo, nullptr, nullptr, d_out, nullptr);
}

// Round 11
// 211.025 us; speedup vs baseline: 1.1363x; 1.1363x over previous
//
#include <hip/hip_runtime.h>

// MHA forward: x[2,4096,768] -> out[2,4096,768], 8 heads, head_dim 96.
// R11: 64 q/wave (halves LDS reads per MFMA; LDS 30us < MFMA 43us per CU)
// + KV-split-2 so the wave count doubles: 512 blocks x 4 waves = 8 waves/CU
// = 2 waves/SIMD (R9/R10 lesson: 64q/wave without split caps at 1 wave/SIMD
// -> serial chain, MfmaUtil 26%). f32 partials + lsum merged by merge_o.
// K/V pre-swizzled in HBM -> global_load_lds staging, dbuf, 1 barrier/tile.

typedef __bf16 bf16;
typedef __attribute__((ext_vector_type(2))) float f32x2;
typedef __attribute__((ext_vector_type(4))) float f32x4;
typedef __attribute__((ext_vector_type(16))) float f32x16;
typedef __attribute__((ext_vector_type(8))) __bf16 bf16x8;
typedef __attribute__((ext_vector_type(4))) __bf16 bf16x4;
typedef __attribute__((ext_vector_type(4))) unsigned u32x4;

#define EMB 768
#define SEQ 4096
#define NB 2
#define NHEADS 8
#define HD 96
#define BHTOT (NB * NHEADS)     // 16
#define MTOT (NB * SEQ)         // 8192
// softmax scale folded into Q gemm epilogue, in exp2 domain:
#define QSCALE 0.14724241052735512f   // 96^-0.5 * log2(e)

#define AS1 __attribute__((address_space(1)))
#define AS3 __attribute__((address_space(3)))

// ---------------- fp32 -> bf16 cast (x) ----------------
__global__ __launch_bounds__(256) void cast_f32_bf16(const float* __restrict__ in,
                                                     bf16* __restrict__ out) {
  const int i = (blockIdx.x * 256 + threadIdx.x) * 4;
  const f32x4 v = *reinterpret_cast<const f32x4*>(in + i);
  bf16x4 o;
  o[0] = (bf16)v[0]; o[1] = (bf16)v[1]; o[2] = (bf16)v[2]; o[3] = (bf16)v[3];
  *reinterpret_cast<bf16x4*>(out + i) = o;
}

// ---------------- fused 4-weight cast ----------------
__global__ __launch_bounds__(256) void cast_w4(const float* __restrict__ w0,
                                               const float* __restrict__ w1,
                                               const float* __restrict__ w2,
                                               const float* __restrict__ w3,
                                               bf16* __restrict__ o0,
                                               bf16* __restrict__ o1,
                                               bf16* __restrict__ o2,
                                               bf16* __restrict__ o3) {
  const float* w = (blockIdx.y == 0) ? w0 : (blockIdx.y == 1) ? w1 : (blockIdx.y == 2) ? w2 : w3;
  bf16* o = (blockIdx.y == 0) ? o0 : (blockIdx.y == 1) ? o1 : (blockIdx.y == 2) ? o2 : o3;
  const int i = (blockIdx.x * 256 + threadIdx.x) * 4;
  const f32x4 v = *reinterpret_cast<const f32x4*>(w + i);
  bf16x4 ob;
  ob[0] = (bf16)v[0]; ob[1] = (bf16)v[1]; ob[2] = (bf16)v[2]; ob[3] = (bf16)v[3];
  *reinterpret_cast<bf16x4*>(o + i) = ob;
}

// ---------------- GEMM ----------------
// MODE 0: fused QKV. B is [2304][768] (Wq;Wk;Wv contiguous).
//   Q (scaled) -> out[bh][n][96]; V -> out + MTOT*EMB, same layout;
//   K -> outK[bh][n][128]: padded row, 16B-slot XOR-swizzled by (n&7).
// MODE 1: C[M,768] = A*Wo^T + b0, fp32 row-major to out.
template <int MODE>
__global__ __launch_bounds__(256) void gemm_bt(const bf16* __restrict__ A,
                                               const bf16* __restrict__ B,
                                               const float* __restrict__ b0,
                                               const float* __restrict__ b1,
                                               const float* __restrict__ b2,
                                               void* __restrict__ out,
                                               void* __restrict__ outK) {
  constexpr int K = EMB;
  __shared__ bf16 As[128 * 32];
  __shared__ bf16 Bs[128 * 32];
  const int tid = threadIdx.x;
  const int lane = tid & 63;
  const int wid = tid >> 6;
  const int wr = wid >> 1, wc = wid & 1;
  const int l15 = lane & 15, l4 = lane >> 4;
  const int rowBase = blockIdx.y * 128;
  const int colBase = blockIdx.x * 128;

  f32x4 acc[4][4] = {};

  for (int kt = 0; kt < K / 32; ++kt) {
    const int kb = kt * 32;
#pragma unroll
    for (int i = 0; i < 2; ++i) {
      const int c = (wid * 2 + i) * 64 + lane;
      const int row = c >> 2, cc = c & 3;
      const bf16* ga = A + (size_t)(rowBase + row) * K + kb + cc * 8;
      const bf16* gb = B + (size_t)(colBase + row) * K + kb + cc * 8;
      __builtin_amdgcn_global_load_lds(
          (const AS1 void*)ga,
          (AS3 void*)(As + (size_t)(wid * 2 + i) * 512), 16, 0, 0);
      __builtin_amdgcn_global_load_lds(
          (const AS1 void*)gb,
          (AS3 void*)(Bs + (size_t)(wid * 2 + i) * 512), 16, 0, 0);
    }
    __syncthreads();
    bf16x8 af[4], bfr[4];
#pragma unroll
    for (int t = 0; t < 4; ++t) {
      af[t]  = *reinterpret_cast<const bf16x8*>(As + (wr * 64 + t * 16 + l15) * 32 + l4 * 8);
      bfr[t] = *reinterpret_cast<const bf16x8*>(Bs + (wc * 64 + t * 16 + l15) * 32 + l4 * 8);
    }
#pragma unroll
    for (int mt = 0; mt < 4; ++mt)
#pragma unroll
      for (int nt = 0; nt < 4; ++nt)
        acc[mt][nt] = __builtin_amdgcn_mfma_f32_16x16x32_bf16(af[mt], bfr[nt], acc[mt][nt], 0, 0, 0);
    __syncthreads();
  }

#pragma unroll
  for (int mt = 0; mt < 4; ++mt) {
#pragma unroll
    for (int nt = 0; nt < 4; ++nt) {
      const int gn = colBase + wc * 64 + nt * 16 + l15;
      if (MODE == 0) {
        const int mm = gn / 768;
        const int g7 = gn - mm * 768;
        const int h = g7 / HD, d = g7 - h * HD;
        const float* bp = (mm == 0) ? b0 : (mm == 1) ? b1 : b2;
        const float bv = bp[g7];
        const float sc = (mm == 0) ? QSCALE : 1.f;
#pragma unroll
        for (int r = 0; r < 4; ++r) {
          const int gm = rowBase + wr * 64 + mt * 16 + l4 * 4 + r;
          const int b = gm >> 12, n = gm & (SEQ - 1);
          const float v = (acc[mt][nt][r] + bv) * sc;
          if (mm == 1) {  // K: padded + swizzled [bh][n][128]
            ((bf16*)outK)[((size_t)(b * NHEADS + h) * SEQ + n) * 128 +
                          (((d >> 3) ^ (n & 7)) << 3) + (d & 7)] = (bf16)v;
          } else {        // Q at 0, V at +MTOT*EMB
            bf16* dst = (bf16*)out + (mm == 2 ? (size_t)MTOT * EMB : 0);
            dst[((size_t)(b * NHEADS + h) * SEQ + n) * HD + d] = (bf16)v;
          }
        }
      } else {
        const float bv = b0[gn];
#pragma unroll
        for (int r = 0; r < 4; ++r) {
          const int gm = rowBase + wr * 64 + mt * 16 + l4 * 4 + r;
          ((float*)out)[(size_t)gm * EMB + gn] = acc[mt][nt][r] + bv;
        }
      }
    }
  }
}

// ---------------- V transpose + ki permute + XOR swizzle ----------------
__global__ __launch_bounds__(256) void transpose_v(const bf16* __restrict__ v,
                                                   bf16* __restrict__ vt) {
  __shared__ bf16 T[96][72];
  const int bh = blockIdx.y;
  const int n0 = blockIdx.x * 64;
  const int tid = threadIdx.x;
#pragma unroll
  for (int i = 0; i < 3; ++i) {
    const int c = i * 256 + tid;
    const int n = c / 12, cc = c % 12;
    const bf16x8 val = *reinterpret_cast<const bf16x8*>(
        v + ((size_t)bh * SEQ + n0 + n) * HD + cc * 8);
#pragma unroll
    for (int j = 0; j < 8; ++j) T[cc * 8 + j][n] = val[j];
  }
  __syncthreads();
#pragma unroll
  for (int i = 0; i < 3; ++i) {
    const int c = i * 256 + tid;
    const int d = c >> 3, nc = c & 7;
    const int s0i = (nc >> 1) * 16 + (nc & 1) * 4;   // ki-permute source
    const bf16x4 lo = *reinterpret_cast<const bf16x4*>(&T[d][s0i]);
    const bf16x4 hi = *reinterpret_cast<const bf16x4*>(&T[d][s0i + 8]);
    const bf16x8 val = __builtin_shufflevector(lo, hi, 0, 1, 2, 3, 4, 5, 6, 7);
    const int pc = nc ^ (d & 7);                     // XOR swizzle
    *reinterpret_cast<bf16x8*>(vt + ((size_t)bh * HD + d) * SEQ + n0 + pc * 8) = val;
  }
}

// ---------------- Flash attention (32x32 MFMA, 64 q/wave, KV-split) -------
// Block = (bh, 256 q, split z), 4 waves x 64 q (2 groups of 32), 256 thr.
// Grid 512 = 2 blocks/CU -> 8 waves/CU = 2 waves/SIMD. KV tile 64, dbuf,
// global_load_lds staging from pre-swizzled HBM. Lane-local softmax (exp2,
// no max tracking). SPLIT==2: f32 partials + lsum; SPLIT==1: bf16 direct.
template <int SPLIT>
__global__ __launch_bounds__(256, 2) void attn_fwd(const bf16* __restrict__ q,
                                                   const bf16* __restrict__ ksw,
                                                   const bf16* __restrict__ vt,
                                                   void* __restrict__ outp,
                                                   float* __restrict__ lsum) {
  __shared__ bf16 Ks[2][64 * 128];   // 2 x 16KB, rows 256B, slot ^= row&7
  __shared__ bf16 Vts[2][96 * 64];   // 2 x 12KB, rows 128B, slot ^= row&7
  const int tid = threadIdx.x;    // 0..255
  const int lane = tid & 63;
  const int wid = tid >> 6;       // 0..3
  const int l31 = lane & 31, lhi = lane >> 5;
  // XCD-chunked bijective remap over 256*SPLIT blocks; decode keeps both
  // splits of a bh on the same XCD: per XCD = 2 full bh (K/V ~3.5MB < L2).
  const int lin = (blockIdx.z * gridDim.y + blockIdx.y) * gridDim.x + blockIdx.x;
  const int nblk = 256 * SPLIT;
  const int cpx = nblk >> 3;                       // blocks per XCD
  const int l2 = (lin & 7) * cpx + (lin >> 3);
  const int qblk = l2 & 15;
  const int z = (SPLIT == 2) ? ((l2 >> 4) & 1) : 0;
  const int bh = (SPLIT == 2) ? (l2 >> 5) : (l2 >> 4);
  const int q0 = qblk * 256 + wid * 64;
  constexpr int NT = SEQ / 64 / SPLIT;
  const int kv00 = z * NT * 64;
  const size_t headq = (size_t)bh * SEQ * HD;
  const bf16* kg = ksw + (size_t)bh * SEQ * 128;
  const bf16* vg = vt + (size_t)bh * (size_t)HD * SEQ;

  // staging source pointers (K image linear per row; V rows of SEQ)
  const bf16* kp = kg + (size_t)kv00 * 128 + (size_t)tid * 8;
  const bf16* vp = vg + (size_t)(tid >> 3) * SEQ + kv00 + (tid & 7) * 8;

  // LDS read byte-offsets (loop-invariant)
  int krd[12], vrd[12];
#pragma unroll
  for (int kib = 0; kib < 2; ++kib)
#pragma unroll
    for (int dc = 0; dc < 6; ++dc) {
      const int row = kib * 32 + l31;
      krd[kib * 6 + dc] = (row * 128 + (((dc * 2 + lhi) ^ (l31 & 7)) * 8)) * 2;
    }
#pragma unroll
  for (int db = 0; db < 3; ++db)
#pragma unroll
    for (int kb = 0; kb < 4; ++kb) {
      const int row = db * 32 + l31;
      vrd[db * 4 + kb] = (row * 64 + (((kb * 2 + lhi) ^ (l31 & 7)) * 8)) * 2;
    }

  // Q B-frags for both q-groups (scale pre-folded into q)
  bf16x8 qf[2][6];
#pragma unroll
  for (int g = 0; g < 2; ++g)
#pragma unroll
    for (int dc = 0; dc < 6; ++dc)
      qf[g][dc] = *reinterpret_cast<const bf16x8*>(
          q + headq + (size_t)(q0 + g * 32 + l31) * HD + dc * 16 + lhi * 8);

  f32x16 oacc[2][3] = {};     // [group][d-block]
  float lrun[2] = {0.f, 0.f};

  // stage tile 0 into buffer 0: K 4 rounds x 4KB, V 3 rounds x 4KB
#pragma unroll
  for (int i = 0; i < 4; ++i)
    __builtin_amdgcn_global_load_lds((const AS1 void*)(kp + i * 2048),
                                     (AS3 void*)(&Ks[0][i * 2048 + tid * 8]), 16, 0, 0);
#pragma unroll
  for (int i = 0; i < 3; ++i)
    __builtin_amdgcn_global_load_lds((const AS1 void*)(vp + (size_t)i * 32 * SEQ),
                                     (AS3 void*)(&Vts[0][i * 2048 + tid * 8]), 16, 0, 0);
  kp += 8192;   // next K tile (64 rows x 128)
  vp += 64;     // next V tile (64 columns)
  __syncthreads();

  for (int kt = 0; kt < NT; ++kt) {
    const int cur = kt & 1;
    // issue next-tile staging into the other buffer (drained by the barrier)
    if (kt < NT - 1) {
#pragma unroll
      for (int i = 0; i < 4; ++i)
        __builtin_amdgcn_global_load_lds((const AS1 void*)(kp + i * 2048),
                                         (AS3 void*)(&Ks[cur ^ 1][i * 2048 + tid * 8]), 16, 0, 0);
#pragma unroll
      for (int i = 0; i < 3; ++i)
        __builtin_amdgcn_global_load_lds((const AS1 void*)(vp + (size_t)i * 32 * SEQ),
                                         (AS3 void*)(&Vts[cur ^ 1][i * 2048 + tid * 8]), 16, 0, 0);
      kp += 8192;
      vp += 64;
    }
    const char* ksb = (const char*)Ks[cur];
    const char* vsb = (const char*)Vts[cur];

    // ---- S^T = K Q^T, softmax, P-pack: per 32-ki block (bounds s regs) ----
    bf16x8 pf[2][4];
#pragma unroll
    for (int kib = 0; kib < 2; ++kib) {
      f32x16 s[2] = {};
      __builtin_amdgcn_s_setprio(1);
#pragma unroll
      for (int dc = 0; dc < 6; ++dc) {
        const bf16x8 kf = *reinterpret_cast<const bf16x8*>(ksb + krd[kib * 6 + dc]);
        s[0] = __builtin_amdgcn_mfma_f32_32x32x16_bf16(kf, qf[0][dc], s[0], 0, 0, 0);
        s[1] = __builtin_amdgcn_mfma_f32_32x32x16_bf16(kf, qf[1][dc], s[1], 0, 0, 0);
      }
      __builtin_amdgcn_s_setprio(0);
#pragma unroll
      for (int g = 0; g < 2; ++g) {
        float a0 = 0.f, a1 = 0.f, a2 = 0.f, a3 = 0.f;
#pragma unroll
        for (int i = 0; i < 4; ++i) {
          s[g][4 * i + 0] = __builtin_amdgcn_exp2f(s[g][4 * i + 0]); a0 += s[g][4 * i + 0];
          s[g][4 * i + 1] = __builtin_amdgcn_exp2f(s[g][4 * i + 1]); a1 += s[g][4 * i + 1];
          s[g][4 * i + 2] = __builtin_amdgcn_exp2f(s[g][4 * i + 2]); a2 += s[g][4 * i + 2];
          s[g][4 * i + 3] = __builtin_amdgcn_exp2f(s[g][4 * i + 3]); a3 += s[g][4 * i + 3];
        }
        lrun[g] += (a0 + a1) + (a2 + a3);
        unsigned c[8];
#pragma unroll
        for (int i = 0; i < 8; ++i)
          asm("v_cvt_pk_bf16_f32 %0, %1, %2"
              : "=v"(c[i]) : "v"(s[g][2 * i]), "v"(s[g][2 * i + 1]));
        const u32x4 wa = {c[0], c[1], c[2], c[3]};
        const u32x4 wb = {c[4], c[5], c[6], c[7]};
        pf[g][kib * 2 + 0] = __builtin_bit_cast(bf16x8, wa);
        pf[g][kib * 2 + 1] = __builtin_bit_cast(bf16x8, wb);
      }
    }

    // ---- O^T += V^T P^T: each V-frag feeds both groups ----
    __builtin_amdgcn_s_setprio(1);
#pragma unroll
    for (int kb = 0; kb < 4; ++kb) {
#pragma unroll
      for (int db = 0; db < 3; ++db) {
        const bf16x8 vf = *reinterpret_cast<const bf16x8*>(vsb + vrd[db * 4 + kb]);
        oacc[0][db] = __builtin_amdgcn_mfma_f32_32x32x16_bf16(vf, pf[0][kb], oacc[0][db], 0, 0, 0);
        oacc[1][db] = __builtin_amdgcn_mfma_f32_32x32x16_bf16(vf, pf[1][kb], oacc[1][db], 0, 0, 0);
      }
    }
    __builtin_amdgcn_s_setprio(0);

    __syncthreads();  // drains staging DMA (vmcnt) + all waves done with cur
  }

  // ---- epilogue ----
  const int b = bh >> 3, h = bh & 7;
#pragma unroll
  for (int g = 0; g < 2; ++g) {
    float lr = lrun[g];
    lr += __shfl_xor(lr, 32, 64);   // combine ki halves
    const int n = q0 + g * 32 + l31;
    if (SPLIT == 2) {
      float* po = (float*)outp + (size_t)z * ((size_t)BHTOT * SEQ * HD) +
                  ((size_t)bh * SEQ + n) * HD;
#pragma unroll
      for (int db = 0; db < 3; ++db)
#pragma unroll
        for (int i = 0; i < 8; ++i) {
          const int r = 2 * i;
          const int d = db * 32 + (r & 3) + 8 * (r >> 2) + 4 * lhi;
          f32x2 w = {oacc[g][db][r], oacc[g][db][r + 1]};
          *reinterpret_cast<f32x2*>(po + d) = w;
        }
      if (lhi == 0) lsum[(size_t)z * BHTOT * SEQ + (size_t)bh * SEQ + n] = lr;
    } else {
      const float inv = 1.f / lr;
      bf16* obase = (bf16*)outp + (size_t)(b * SEQ + n) * EMB + h * HD;
#pragma unroll
      for (int db = 0; db < 3; ++db)
#pragma unroll
        for (int i = 0; i < 8; ++i) {
          const int r = 2 * i;
          const int d = db * 32 + (r & 3) + 8 * (r >> 2) + 4 * lhi;
          unsigned w;
          const float v0 = oacc[g][db][r] * inv, v1 = oacc[g][db][r + 1] * inv;
          asm("v_cvt_pk_bf16_f32 %0, %1, %2" : "=v"(w) : "v"(v0), "v"(v1));
          *reinterpret_cast<unsigned*>(obase + d) = w;
        }
    }
  }
}

// ---------------- merge split partials: O = (P0+P1)/(L0+L1) ----------------
__global__ __launch_bounds__(256) void merge_o(const float* __restrict__ p,
                                               const float* __restrict__ ls,
                                               bf16* __restrict__ ao) {
  const int idx = blockIdx.x * 256 + threadIdx.x;   // one per 4 d-elements
  const size_t PS = (size_t)BHTOT * SEQ * HD;
  const f32x4 a = *reinterpret_cast<const f32x4*>(p + (size_t)idx * 4);
  const f32x4 b2 = *reinterpret_cast<const f32x4*>(p + PS + (size_t)idx * 4);
  const int rest = idx / 24;            // bh*SEQ + n
  const int d4 = idx - rest * 24;
  const float inv = 1.f / (ls[rest] + ls[BHTOT * SEQ + rest]);
  const int bh = rest >> 12, n = rest & (SEQ - 1);
  const int b = bh >> 3, h = bh & 7;
  bf16x4 o4;
#pragma unroll
  for (int j = 0; j < 4; ++j) o4[j] = (bf16)((a[j] + b2[j]) * inv);
  *reinterpret_cast<bf16x4*>(ao + (size_t)(b * SEQ + n) * EMB + h * HD + d4 * 4) = o4;
}

// ---------------- launch ----------------
extern "C" void kernel_launch(void* const* d_in, const int* in_sizes, int n_in,
                              void* d_out, int out_size, void* d_ws, size_t ws_size,
                              hipStream_t stream) {
  const float* x  = (const float*)d_in[0];
  const float* Wq = (const float*)d_in[1];
  const float* bq = (const float*)d_in[2];
  const float* Wk = (const float*)d_in[3];
  const float* bk = (const float*)d_in[4];
  const float* Wv = (const float*)d_in[5];
  const float* bv = (const float*)d_in[6];
  const float* Wo = (const float*)d_in[7];
  const float* bo = (const float*)d_in[8];

  const size_t XN = (size_t)MTOT * EMB;        // 6291456
  const size_t WN = (size_t)EMB * EMB;         // 589824
  const size_t KSWN = (size_t)BHTOT * SEQ * 128;  // 8388608 (padded K)

  bf16* p = (bf16*)d_ws;
  bf16* xbf  = p; p += XN;
  bf16* wqb  = p; p += WN;   // wq/wk/wv contiguous -> fused B [2304][768]
  bf16* wkb  = p; p += WN;
  bf16* wvb  = p; p += WN;
  bf16* wob  = p; p += WN;
  bf16* qb   = p; p += XN;   // Q [bh][n][96]
  bf16* vb   = p; p += XN;   // V [bh][n][96]  (qb and vb contiguous)
  bf16* kbsw = p; p += KSWN; // K padded+swizzled [bh][n][128]
  bf16* vtb  = p; p += XN;   // Vt permuted+swizzled [bh][96][n]
  bf16* ao   = p; p += XN;   // attention output [m][768]
  const size_t base_bytes = (size_t)((char*)p - (char*)d_ws);
  float* part = (float*)p;                       // 2 * BHTOT*SEQ*HD f32
  float* lsum = part + 2 * ((size_t)BHTOT * SEQ * HD);
  const size_t need2 = base_bytes + (2 * (size_t)BHTOT * SEQ * HD) * 4 +
                       (2 * (size_t)BHTOT * SEQ) * 4;
  const bool split2 = (ws_size >= need2);

  cast_f32_bf16<<<XN / 1024, 256, 0, stream>>>(x, xbf);
  cast_w4<<<dim3(WN / 1024, 4), 256, 0, stream>>>(Wq, Wk, Wv, Wo, wqb, wkb, wvb, wob);

  gemm_bt<0><<<dim3(3 * EMB / 128, MTOT / 128), 256, 0, stream>>>(
      xbf, wqb, bq, bk, bv, qb, kbsw);

  transpose_v<<<dim3(SEQ / 64, BHTOT), 256, 0, stream>>>(vb, vtb);

  if (split2) {
    attn_fwd<2><<<dim3(16, 16, 2), 256, 0, stream>>>(qb, kbsw, vtb, part, lsum);
    merge_o<<<(BHTOT * SEQ * HD / 4) / 256, 256, 0, stream>>>(part, lsum, ao);
  } else {
    attn_fwd<1><<<dim3(16, 16, 1), 256, 0, stream>>>(qb, kbsw, vtb, ao, nullptr);
  }

  gemm_bt<1><<<dim3(EMB / 128, MTOT / 128), 256, 0, stream>>>(
      ao, wob, bo, nullptr, nullptr, d_out, nullptr);
}